// Round 8
// baseline (136.004 us; speedup 1.0000x reference)
//
#include <hip/hip_runtime.h>
#include <hip/hip_fp16.h>

#define NN 4
#define CC 256
#define PP 2304   // 48*48
#define EPSV 1e-5f

typedef __attribute__((ext_vector_type(8))) short bf16x8;
typedef __attribute__((ext_vector_type(4))) float f32x4;

struct alignas(8) h4 { __half2 a, b; };

// monotone float<->uint encoding: uint atomicMin/Max == float min/max
__device__ inline unsigned fenc(float f) {
  unsigned b = __float_as_uint(f);
  return (b & 0x80000000u) ? ~b : (b | 0x80000000u);
}
__device__ inline float fdec(unsigned e) {
  unsigned b = (e & 0x80000000u) ? (e ^ 0x80000000u) : ~e;
  return __uint_as_float(b);
}

__device__ inline unsigned short f2bf(float x) {  // RNE float->bf16
  unsigned u = __float_as_uint(x);
  unsigned r = (u + 0x7FFFu + ((u >> 16) & 1u)) >> 16;
  return (unsigned short)r;
}

// async global->LDS, 16B per lane; LDS dest = wave-uniform base + lane*16
__device__ inline void gload_lds16(const unsigned short* g, unsigned short* l) {
  __builtin_amdgcn_global_load_lds(
      (const __attribute__((address_space(1))) void*)g,
      (__attribute__((address_space(3))) void*)l, 16, 0, 0);
}

// Kernel 1: per-(c,n) partial channel sums of fT (float4 loads, no atomics);
// inits divu/cxsum. k_norm combines the 4 partials per channel.
__global__ __launch_bounds__(256) void k_mean(const float* __restrict__ fT,
                                              float* __restrict__ partial,
                                              unsigned* __restrict__ divu,
                                              float* __restrict__ cxsum) {
  int c = blockIdx.x, n = blockIdx.y, t = threadIdx.x;
  const float4* base = (const float4*)(fT + ((size_t)n * CC + c) * PP);  // 576 float4
  float s = 0.f;
  for (int k = t; k < 576; k += 256) {
    float4 v = base[k];
    s += (v.x + v.y) + (v.z + v.w);
  }
  for (int o = 32; o > 0; o >>= 1) s += __shfl_down(s, o);
  __shared__ float red[4];
  if ((t & 63) == 0) red[t >> 6] = s;
  __syncthreads();
  if (t == 0) partial[c * NN + n] = red[0] + red[1] + red[2] + red[3];
  if (n == 0 && t < 36) divu[c * 36 + t] = 0xFFFFFFFFu;  // encoded +inf
  if (n == 0 && c == 0 && t < 4) cxsum[t] = 0.f;
}

// Kernel 2: center by mean (combined from partials), l2-normalize over C,
// transpose to [N][P][C] bf16. float4 global loads along p.
__global__ __launch_bounds__(256) void k_norm(const float* __restrict__ fT,
                                              const float* __restrict__ fI,
                                              const float* __restrict__ partial,
                                              unsigned short* __restrict__ A,
                                              unsigned short* __restrict__ B) {
  int n = blockIdx.y;
  int p0 = blockIdx.x * 16;
  int t = threadIdx.x;
  int pq = (t & 3) * 4;   // p-quad base 0,4,8,12
  int cg = t >> 2;        // c-group 0..63
  __shared__ float cT[16][257];
  __shared__ float cI[16][257];
  __shared__ float redf[2][16][65];
  __shared__ float inv[2][16];
  float aT[4] = {0.f, 0.f, 0.f, 0.f}, aI[4] = {0.f, 0.f, 0.f, 0.f};
#pragma unroll
  for (int ph = 0; ph < 4; ph++) {
    int c = ph * 64 + cg;
    float m = (partial[c * NN + 0] + partial[c * NN + 1] +
               partial[c * NN + 2] + partial[c * NN + 3]) * (1.0f / (float)(NN * PP));
    size_t g = ((size_t)n * CC + c) * PP + p0 + pq;
    float4 vT = *(const float4*)(fT + g);
    float4 vI = *(const float4*)(fI + g);
    float xT[4] = {vT.x - m, vT.y - m, vT.z - m, vT.w - m};
    float xI[4] = {vI.x - m, vI.y - m, vI.z - m, vI.w - m};
#pragma unroll
    for (int k = 0; k < 4; k++) {
      cT[pq + k][c] = xT[k]; cI[pq + k][c] = xI[k];
      aT[k] += xT[k] * xT[k]; aI[k] += xI[k] * xI[k];
    }
  }
#pragma unroll
  for (int k = 0; k < 4; k++) {
    redf[0][pq + k][cg] = aT[k];
    redf[1][pq + k][cg] = aI[k];
  }
  __syncthreads();
  if (t < 32) {
    int which = t >> 4, p = t & 15;
    float s = 0.f;
    for (int g = 0; g < 64; g++) s += redf[which][p][g];
    inv[which][p] = 1.0f / sqrtf(s);
  }
  __syncthreads();
#pragma unroll
  for (int it = 0; it < 2; it++) {
    int task = it * 256 + t;
    int ps = task >> 5;       // patch 0..15
    int ch = task & 31;       // chunk of 8 channels
    float iA = inv[0][ps], iB = inv[1][ps];
    unsigned short va[8], vb[8];
#pragma unroll
    for (int e = 0; e < 8; e++) {
      va[e] = f2bf(cT[ps][ch * 8 + e] * iA);
      vb[e] = f2bf(cI[ps][ch * 8 + e] * iB);
    }
    size_t o = ((size_t)(n * PP + p0 + ps)) * CC + ch * 8;
    *(int4*)(A + o) = *(const int4*)va;
    *(int4*)(B + o) = *(const int4*)vb;
  }
}

// Kernel 3: per-sample GEMM G = A·B^T, 128x128 tile, BK=64, global_load_lds
// staging w/ XOR swizzle. Epilogue writes TRANSPOSED raw_t[j][i]=(1-G)/2 fp16
// via b64-packed LDS transpose + coalesced int4 stores; fused col-min -> divu.
__global__ __launch_bounds__(256) void k_gemm(const unsigned short* __restrict__ A,
                                              const unsigned short* __restrict__ B,
                                              __half* __restrict__ rawt,
                                              unsigned* __restrict__ divu) {
  int n  = blockIdx.z;
  int i0 = blockIdx.y * 128;
  int j0 = blockIdx.x * 128;
  int t  = threadIdx.x;
  int lane = t & 63;
  int w = t >> 6;
  int wi = w >> 1, wj = w & 1;           // wave quadrant (2x2 of 64x64)
  int lr = lane & 15, lq = lane >> 4;

  __shared__ __align__(16) char smem[33792];
  unsigned short* As = (unsigned short*)smem;            // slots 0..1023, 16B each
  unsigned short* Bs = (unsigned short*)(smem + 16384);
  __half* r16t = (__half*)smem;                          // [128][132]
  __shared__ unsigned cmin[128];
  if (t < 128) cmin[t] = 0xFFFFFFFFu;

  f32x4 acc[4][4];
#pragma unroll
  for (int a = 0; a < 4; a++)
#pragma unroll
    for (int b = 0; b < 4; b++) acc[a][b] = (f32x4){0.f, 0.f, 0.f, 0.f};

  const size_t baseA = ((size_t)(n * PP + i0)) * CC;
  const size_t baseB = ((size_t)(n * PP + j0)) * CC;
  int lrow8 = lane >> 3;
  int lseg  = (lane & 7) ^ (lrow8 & 7);   // XOR-swizzled source seg

  for (int k0 = 0; k0 < CC; k0 += 64) {
    if (k0) __syncthreads();
#pragma unroll
    for (int it = 0; it < 4; it++) {
      int sb = (w * 4 + it) * 64;
      int row = (w * 4 + it) * 8 + lrow8;
      gload_lds16(A + baseA + (size_t)row * CC + k0 + lseg * 8, As + sb * 8);
      gload_lds16(B + baseB + (size_t)row * CC + k0 + lseg * 8, Bs + sb * 8);
    }
    __syncthreads();
#pragma unroll
    for (int ks = 0; ks < 2; ks++) {
      bf16x8 af[4], bf[4];
#pragma unroll
      for (int ti = 0; ti < 4; ti++) {
        int row = wi * 64 + ti * 16 + lr;
        int slot = row * 8 + ((ks * 4 + lq) ^ (lr & 7));
        af[ti] = *(const bf16x8*)&As[slot * 8];
      }
#pragma unroll
      for (int tj = 0; tj < 4; tj++) {
        int row = wj * 64 + tj * 16 + lr;
        int slot = row * 8 + ((ks * 4 + lq) ^ (lr & 7));
        bf[tj] = *(const bf16x8*)&Bs[slot * 8];
      }
#pragma unroll
      for (int ti = 0; ti < 4; ti++)
#pragma unroll
        for (int tj = 0; tj < 4; tj++)
          acc[ti][tj] = __builtin_amdgcn_mfma_f32_16x16x32_bf16(af[ti], bf[tj], acc[ti][tj], 0, 0, 0);
    }
  }

  __syncthreads();  // done with As/Bs; smem becomes r16t
  // C/D layout col=lane&15, row=(lane>>4)*4+reg  [m89/m91 verified]
#pragma unroll
  for (int tj = 0; tj < 4; tj++) {
    float mx = -1e30f;
    int cj = wj * 64 + tj * 16 + lr;
#pragma unroll
    for (int ti = 0; ti < 4; ti++) {
      alignas(8) unsigned short pk[4];
#pragma unroll
      for (int r = 0; r < 4; r++) {
        float g = acc[ti][tj][r];
        mx = fmaxf(mx, g);
        pk[r] = __half_as_ushort(__float2half((1.0f - g) * 0.5f));
      }
      int ci = wi * 64 + ti * 16 + lq * 4;
      *(short4*)&r16t[cj * 132 + ci] = *(const short4*)pk;  // b64, conflict-free
    }
    atomicMin(&cmin[cj], fenc((1.0f - mx) * 0.5f));  // min raw == (1-max G)/2
  }
  __syncthreads();
#pragma unroll
  for (int m = 0; m < 8; m++) {
    int chunk = m * 256 + t;
    int row = chunk >> 4, cs = chunk & 15;
    int2 lo = *(const int2*)&r16t[row * 132 + cs * 8];
    int2 hi = *(const int2*)&r16t[row * 132 + cs * 8 + 4];
    int4 v = {lo.x, lo.y, hi.x, hi.y};
    *(int4*)(rawt + ((size_t)(n * PP + j0 + row)) * PP + i0 + cs * 8) = v;
  }
  if (t < 128) atomicMin(&divu[n * PP + j0 + t], cmin[t]);
}

// Kernel 4: per j-row: S = sum_i exp(sc_j*raw_t[j][i]); writes scale_j and
// lnS_j directly (logscale fused). One wave per row, wave-uniform sc_j.
__global__ __launch_bounds__(256) void k_colsum(const __half* __restrict__ rawt,
                                                const unsigned* __restrict__ divu,
                                                float* __restrict__ scale,
                                                float* __restrict__ lnS) {
  int t = threadIdx.x, lane = t & 63, w = t >> 6;
  int r = blockIdx.x * 4 + w;      // global j-row 0..9215
  float d = fdec(divu[r]);
  float sc = -10.0f / (d + EPSV);
  const __half* rp = rawt + (size_t)r * PP;
  float s = 0.f;
#pragma unroll
  for (int c = 0; c < 9; c++) {
    h4 hv = *(const h4*)(rp + c * 256 + lane * 4);
    float2 f01 = __half22float2(hv.a);
    float2 f23 = __half22float2(hv.b);
    s += __expf(f01.x * sc) + __expf(f01.y * sc) + __expf(f23.x * sc) + __expf(f23.y * sc);
  }
  for (int o = 32; o > 0; o >>= 1) s += __shfl_down(s, o);
  if (lane == 0) {
    scale[r] = sc;
    lnS[r] = logf(s);
  }
}

// Kernel 5: each block owns 16 i's x ALL j (balanced: 576 blocks ~ 2.25/CU
// vs 288 blocks' 2x tail). M_i completes in-block -> exp -> one atomicAdd.
__global__ __launch_bounds__(256) void k_rowmax(const __half* __restrict__ rawt,
                                                const float* __restrict__ scale,
                                                const float* __restrict__ lnS,
                                                float* __restrict__ cxsum) {
  int n = blockIdx.y;
  int i0 = blockIdx.x * 16;
  int t = threadIdx.x, lane = t & 63, w = t >> 6;
  int q = lane & 3;                // i-quad 0..3 -> i = i0 + q*4
  int g = w * 16 + (lane >> 2);    // j-group 0..63
  int i = i0 + q * 4;
  const float* scp = scale + n * PP;
  const float* lnp = lnS + n * PP;
  float m0 = -1e30f, m1 = -1e30f, m2 = -1e30f, m3 = -1e30f;
#pragma unroll 4
  for (int it = 0; it < 36; it++) {
    int j = it * 64 + g;
    float scj = scp[j], lsj = lnp[j];
    h4 hv = *(const h4*)(rawt + ((size_t)(n * PP + j)) * PP + i);
    float2 f01 = __half22float2(hv.a);
    float2 f23 = __half22float2(hv.b);
    m0 = fmaxf(m0, fmaf(f01.x, scj, -lsj));
    m1 = fmaxf(m1, fmaf(f01.y, scj, -lsj));
    m2 = fmaxf(m2, fmaf(f23.x, scj, -lsj));
    m3 = fmaxf(m3, fmaf(f23.y, scj, -lsj));
  }
  // reduce over j-group bits within wave (lane bits 2..5)
#pragma unroll
  for (int o = 4; o <= 32; o <<= 1) {
    m0 = fmaxf(m0, __shfl_xor(m0, o));
    m1 = fmaxf(m1, __shfl_xor(m1, o));
    m2 = fmaxf(m2, __shfl_xor(m2, o));
    m3 = fmaxf(m3, __shfl_xor(m3, o));
  }
  __shared__ float red[4][4][4];   // [wave][q][elem]
  if (lane < 4) {
    red[w][lane][0] = m0; red[w][lane][1] = m1;
    red[w][lane][2] = m2; red[w][lane][3] = m3;
  }
  __syncthreads();
  if (t < 16) {                    // t = q*4+e -> one i each
    float M = red[0][t >> 2][t & 3];
#pragma unroll
    for (int ww = 1; ww < 4; ww++) M = fmaxf(M, red[ww][t >> 2][t & 3]);
    float v = __expf(M) * (1.0f / (float)PP);
    v += __shfl_down(v, 8); v += __shfl_down(v, 4);
    v += __shfl_down(v, 2); v += __shfl_down(v, 1);
    if (t == 0) atomicAdd(&cxsum[n], v);
  }
}

// Kernel 6: CX_B = -log(cxsum), loss = mean
__global__ void k_final(const float* __restrict__ cxsum, float* __restrict__ out) {
  int t = threadIdx.x;
  float cxb = 0.f;
  if (t < 4) {
    cxb = -logf(cxsum[t]);
    out[1 + t] = cxb;
  }
  for (int o = 2; o > 0; o >>= 1) cxb += __shfl_down(cxb, o);
  if (t == 0) out[0] = cxb * 0.25f;
}

extern "C" void kernel_launch(void* const* d_in, const int* in_sizes, int n_in,
                              void* d_out, int out_size, void* d_ws, size_t ws_size,
                              hipStream_t stream) {
  const float* fT = (const float*)d_in[0];
  const float* fI = (const float*)d_in[1];
  float* out = (float*)d_out;

  char* w = (char*)d_ws;
  float* partial = (float*)w;                                    // 4096 B
  unsigned* divu = (unsigned*)(w + 4096);                        // 36864 B
  float* scale   = (float*)(w + 4096 + 36864);                   // 36864 B
  float* lnS     = (float*)(w + 4096 + 2 * 36864);               // 36864 B
  float* cxsum   = (float*)(w + 4096 + 3 * 36864);               // pad to 1024
  size_t off = 4096 + 3 * 36864 + 1024;                          // 115712
  unsigned short* A = (unsigned short*)(w + off);                // 4718592 B
  unsigned short* B = (unsigned short*)(w + off + 4718592);      // 4718592 B
  __half* rawt = (__half*)(w + off + 2 * 4718592);               // 42467328 B

  k_mean<<<dim3(CC, NN), 256, 0, stream>>>(fT, partial, divu, cxsum);
  k_norm<<<dim3(PP / 16, NN), 256, 0, stream>>>(fT, fI, partial, A, B);
  k_gemm<<<dim3(PP / 128, PP / 128, NN), 256, 0, stream>>>(A, B, rawt, divu);
  k_colsum<<<dim3(PP * NN / 4), 256, 0, stream>>>(rawt, divu, scale, lnS);
  k_rowmax<<<dim3(PP / 16, NN), 256, 0, stream>>>(rawt, scale, lnS, cxsum);
  k_final<<<1, 64, 0, stream>>>(cxsum, out);
}

// Round 9
// 123.453 us; speedup vs baseline: 1.1017x; 1.1017x over previous
//
#include <hip/hip_runtime.h>
#include <hip/hip_fp16.h>

#define NN 4
#define CC 256
#define PP 2304   // 48*48
#define EPSV 1e-5f

typedef __attribute__((ext_vector_type(8))) short bf16x8;
typedef __attribute__((ext_vector_type(4))) float f32x4;

struct alignas(8) h4 { __half2 a, b; };
struct alignas(16) h8 { __half2 a, b, c, d; };

// monotone float<->uint encoding: uint atomicMin/Max == float min/max
__device__ inline unsigned fenc(float f) {
  unsigned b = __float_as_uint(f);
  return (b & 0x80000000u) ? ~b : (b | 0x80000000u);
}
__device__ inline float fdec(unsigned e) {
  unsigned b = (e & 0x80000000u) ? (e ^ 0x80000000u) : ~e;
  return __uint_as_float(b);
}

__device__ inline unsigned short f2bf(float x) {  // RNE float->bf16
  unsigned u = __float_as_uint(x);
  unsigned r = (u + 0x7FFFu + ((u >> 16) & 1u)) >> 16;
  return (unsigned short)r;
}

// async global->LDS, 16B per lane; LDS dest = wave-uniform base + lane*16
__device__ inline void gload_lds16(const unsigned short* g, unsigned short* l) {
  __builtin_amdgcn_global_load_lds(
      (const __attribute__((address_space(1))) void*)g,
      (__attribute__((address_space(3))) void*)l, 16, 0, 0);
}

// Kernel 1: per-(c,n) partial channel sums of fT (float4 loads, no atomics);
// inits divu/cxsum. k_norm combines the 4 partials per channel.
__global__ __launch_bounds__(256) void k_mean(const float* __restrict__ fT,
                                              float* __restrict__ partial,
                                              unsigned* __restrict__ divu,
                                              float* __restrict__ cxsum) {
  int c = blockIdx.x, n = blockIdx.y, t = threadIdx.x;
  const float4* base = (const float4*)(fT + ((size_t)n * CC + c) * PP);  // 576 float4
  float s = 0.f;
  for (int k = t; k < 576; k += 256) {
    float4 v = base[k];
    s += (v.x + v.y) + (v.z + v.w);
  }
  for (int o = 32; o > 0; o >>= 1) s += __shfl_down(s, o);
  __shared__ float red[4];
  if ((t & 63) == 0) red[t >> 6] = s;
  __syncthreads();
  if (t == 0) partial[c * NN + n] = red[0] + red[1] + red[2] + red[3];
  if (n == 0 && t < 36) divu[c * 36 + t] = 0xFFFFFFFFu;  // encoded +inf
  if (n == 0 && c == 0 && t < 4) cxsum[t] = 0.f;
}

// Kernel 2: center by mean (combined from partials), l2-normalize over C,
// transpose to [N][P][C] bf16. float4 global loads along p.
__global__ __launch_bounds__(256) void k_norm(const float* __restrict__ fT,
                                              const float* __restrict__ fI,
                                              const float* __restrict__ partial,
                                              unsigned short* __restrict__ A,
                                              unsigned short* __restrict__ B) {
  int n = blockIdx.y;
  int p0 = blockIdx.x * 16;
  int t = threadIdx.x;
  int pq = (t & 3) * 4;   // p-quad base 0,4,8,12
  int cg = t >> 2;        // c-group 0..63
  __shared__ float cT[16][257];
  __shared__ float cI[16][257];
  __shared__ float redf[2][16][65];
  __shared__ float inv[2][16];
  float aT[4] = {0.f, 0.f, 0.f, 0.f}, aI[4] = {0.f, 0.f, 0.f, 0.f};
#pragma unroll
  for (int ph = 0; ph < 4; ph++) {
    int c = ph * 64 + cg;
    float m = (partial[c * NN + 0] + partial[c * NN + 1] +
               partial[c * NN + 2] + partial[c * NN + 3]) * (1.0f / (float)(NN * PP));
    size_t g = ((size_t)n * CC + c) * PP + p0 + pq;
    float4 vT = *(const float4*)(fT + g);
    float4 vI = *(const float4*)(fI + g);
    float xT[4] = {vT.x - m, vT.y - m, vT.z - m, vT.w - m};
    float xI[4] = {vI.x - m, vI.y - m, vI.z - m, vI.w - m};
#pragma unroll
    for (int k = 0; k < 4; k++) {
      cT[pq + k][c] = xT[k]; cI[pq + k][c] = xI[k];
      aT[k] += xT[k] * xT[k]; aI[k] += xI[k] * xI[k];
    }
  }
#pragma unroll
  for (int k = 0; k < 4; k++) {
    redf[0][pq + k][cg] = aT[k];
    redf[1][pq + k][cg] = aI[k];
  }
  __syncthreads();
  if (t < 32) {
    int which = t >> 4, p = t & 15;
    float s = 0.f;
    for (int g = 0; g < 64; g++) s += redf[which][p][g];
    inv[which][p] = 1.0f / sqrtf(s);
  }
  __syncthreads();
#pragma unroll
  for (int it = 0; it < 2; it++) {
    int task = it * 256 + t;
    int ps = task >> 5;       // patch 0..15
    int ch = task & 31;       // chunk of 8 channels
    float iA = inv[0][ps], iB = inv[1][ps];
    unsigned short va[8], vb[8];
#pragma unroll
    for (int e = 0; e < 8; e++) {
      va[e] = f2bf(cT[ps][ch * 8 + e] * iA);
      vb[e] = f2bf(cI[ps][ch * 8 + e] * iB);
    }
    size_t o = ((size_t)(n * PP + p0 + ps)) * CC + ch * 8;
    *(int4*)(A + o) = *(const int4*)va;
    *(int4*)(B + o) = *(const int4*)vb;
  }
}

// Kernel 3: per-sample GEMM G = A·B^T, 128x128 tile, BK=64, global_load_lds
// staging w/ XOR swizzle. Epilogue writes TRANSPOSED raw_t[j][i]=(1-G)/2 fp16
// via b64-packed LDS transpose + coalesced int4 stores; fused col-min -> divu.
__global__ __launch_bounds__(256) void k_gemm(const unsigned short* __restrict__ A,
                                              const unsigned short* __restrict__ B,
                                              __half* __restrict__ rawt,
                                              unsigned* __restrict__ divu) {
  int n  = blockIdx.z;
  int i0 = blockIdx.y * 128;
  int j0 = blockIdx.x * 128;
  int t  = threadIdx.x;
  int lane = t & 63;
  int w = t >> 6;
  int wi = w >> 1, wj = w & 1;           // wave quadrant (2x2 of 64x64)
  int lr = lane & 15, lq = lane >> 4;

  __shared__ __align__(16) char smem[33792];
  unsigned short* As = (unsigned short*)smem;            // slots 0..1023, 16B each
  unsigned short* Bs = (unsigned short*)(smem + 16384);
  __half* r16t = (__half*)smem;                          // [128][132]
  __shared__ unsigned cmin[128];
  if (t < 128) cmin[t] = 0xFFFFFFFFu;

  f32x4 acc[4][4];
#pragma unroll
  for (int a = 0; a < 4; a++)
#pragma unroll
    for (int b = 0; b < 4; b++) acc[a][b] = (f32x4){0.f, 0.f, 0.f, 0.f};

  const size_t baseA = ((size_t)(n * PP + i0)) * CC;
  const size_t baseB = ((size_t)(n * PP + j0)) * CC;
  int lrow8 = lane >> 3;
  int lseg  = (lane & 7) ^ (lrow8 & 7);   // XOR-swizzled source seg

  for (int k0 = 0; k0 < CC; k0 += 64) {
    if (k0) __syncthreads();
#pragma unroll
    for (int it = 0; it < 4; it++) {
      int sb = (w * 4 + it) * 64;
      int row = (w * 4 + it) * 8 + lrow8;
      gload_lds16(A + baseA + (size_t)row * CC + k0 + lseg * 8, As + sb * 8);
      gload_lds16(B + baseB + (size_t)row * CC + k0 + lseg * 8, Bs + sb * 8);
    }
    __syncthreads();
#pragma unroll
    for (int ks = 0; ks < 2; ks++) {
      bf16x8 af[4], bf[4];
#pragma unroll
      for (int ti = 0; ti < 4; ti++) {
        int row = wi * 64 + ti * 16 + lr;
        int slot = row * 8 + ((ks * 4 + lq) ^ (lr & 7));
        af[ti] = *(const bf16x8*)&As[slot * 8];
      }
#pragma unroll
      for (int tj = 0; tj < 4; tj++) {
        int row = wj * 64 + tj * 16 + lr;
        int slot = row * 8 + ((ks * 4 + lq) ^ (lr & 7));
        bf[tj] = *(const bf16x8*)&Bs[slot * 8];
      }
#pragma unroll
      for (int ti = 0; ti < 4; ti++)
#pragma unroll
        for (int tj = 0; tj < 4; tj++)
          acc[ti][tj] = __builtin_amdgcn_mfma_f32_16x16x32_bf16(af[ti], bf[tj], acc[ti][tj], 0, 0, 0);
    }
  }

  __syncthreads();  // done with As/Bs; smem becomes r16t
  // C/D layout col=lane&15, row=(lane>>4)*4+reg  [m89/m91 verified]
#pragma unroll
  for (int tj = 0; tj < 4; tj++) {
    float mx = -1e30f;
    int cj = wj * 64 + tj * 16 + lr;
#pragma unroll
    for (int ti = 0; ti < 4; ti++) {
      alignas(8) unsigned short pk[4];
#pragma unroll
      for (int r = 0; r < 4; r++) {
        float g = acc[ti][tj][r];
        mx = fmaxf(mx, g);
        pk[r] = __half_as_ushort(__float2half((1.0f - g) * 0.5f));
      }
      int ci = wi * 64 + ti * 16 + lq * 4;
      *(short4*)&r16t[cj * 132 + ci] = *(const short4*)pk;  // b64, conflict-free
    }
    atomicMin(&cmin[cj], fenc((1.0f - mx) * 0.5f));  // min raw == (1-max G)/2
  }
  __syncthreads();
#pragma unroll
  for (int m = 0; m < 8; m++) {
    int chunk = m * 256 + t;
    int row = chunk >> 4, cs = chunk & 15;
    int2 lo = *(const int2*)&r16t[row * 132 + cs * 8];
    int2 hi = *(const int2*)&r16t[row * 132 + cs * 8 + 4];
    int4 v = {lo.x, lo.y, hi.x, hi.y};
    *(int4*)(rawt + ((size_t)(n * PP + j0 + row)) * PP + i0 + cs * 8) = v;
  }
  if (t < 128) atomicMin(&divu[n * PP + j0 + t], cmin[t]);
}

// Kernel 4: per j-row: S = sum_i exp(sc_j*raw_t[j][i]); writes scale_j and
// lnS_j directly (logscale fused). One wave per row, wave-uniform sc_j.
// h8 (16B) vector loads: 4 full chunks + 256-half tail.
__global__ __launch_bounds__(256) void k_colsum(const __half* __restrict__ rawt,
                                                const unsigned* __restrict__ divu,
                                                float* __restrict__ scale,
                                                float* __restrict__ lnS) {
  int t = threadIdx.x, lane = t & 63, w = t >> 6;
  int r = blockIdx.x * 4 + w;      // global j-row 0..9215
  float d = fdec(divu[r]);
  float sc = -10.0f / (d + EPSV);
  const __half* rp = rawt + (size_t)r * PP;
  float s = 0.f;
#pragma unroll
  for (int c = 0; c < 4; c++) {    // 4 x (64 lanes x 8 halfs) = 2048
    h8 hv = *(const h8*)(rp + c * 512 + lane * 8);
    float2 f0 = __half22float2(hv.a), f1 = __half22float2(hv.b);
    float2 f2 = __half22float2(hv.c), f3 = __half22float2(hv.d);
    s += __expf(f0.x * sc) + __expf(f0.y * sc) + __expf(f1.x * sc) + __expf(f1.y * sc);
    s += __expf(f2.x * sc) + __expf(f2.y * sc) + __expf(f3.x * sc) + __expf(f3.y * sc);
  }
  {                                 // tail 256: 64 lanes x 4 halfs
    h4 hv = *(const h4*)(rp + 2048 + lane * 4);
    float2 f01 = __half22float2(hv.a), f23 = __half22float2(hv.b);
    s += __expf(f01.x * sc) + __expf(f01.y * sc) + __expf(f23.x * sc) + __expf(f23.y * sc);
  }
  for (int o = 32; o > 0; o >>= 1) s += __shfl_down(s, o);
  if (lane == 0) {
    scale[r] = sc;
    lnS[r] = logf(s);
  }
}

// Kernel 5 (round-6 measured-best version): each block owns 32 i's x ALL j.
// M_i completes in-block -> exp + reduce -> one atomicAdd to cxsum[n].
// Block=512 (8 waves), q=t&7 picks i-quad (8-lane x 8B = 64B clusters),
// g=t>>3 picks j-group; sc_j/lnS_j uniform per group.
__global__ __launch_bounds__(512) void k_rowmax(const __half* __restrict__ rawt,
                                                const float* __restrict__ scale,
                                                const float* __restrict__ lnS,
                                                float* __restrict__ cxsum) {
  int n = blockIdx.y;
  int i0 = blockIdx.x * 32;
  int t = threadIdx.x, lane = t & 63, w = t >> 6;
  int q = t & 7, g = t >> 3;       // i-quad 0..7, j-group 0..63
  int i = i0 + q * 4;
  const float* scp = scale + n * PP;
  const float* lnp = lnS + n * PP;
  float m0 = -1e30f, m1 = -1e30f, m2 = -1e30f, m3 = -1e30f;
#pragma unroll 4
  for (int it = 0; it < 36; it++) {
    int j = it * 64 + g;
    float scj = scp[j], lsj = lnp[j];
    h4 hv = *(const h4*)(rawt + ((size_t)(n * PP + j)) * PP + i);
    float2 f01 = __half22float2(hv.a);
    float2 f23 = __half22float2(hv.b);
    m0 = fmaxf(m0, fmaf(f01.x, scj, -lsj));
    m1 = fmaxf(m1, fmaf(f01.y, scj, -lsj));
    m2 = fmaxf(m2, fmaf(f23.x, scj, -lsj));
    m3 = fmaxf(m3, fmaf(f23.y, scj, -lsj));
  }
  // butterfly over j-group bits within wave (bits 3..5 of lane)
#pragma unroll
  for (int o = 8; o <= 32; o <<= 1) {
    m0 = fmaxf(m0, __shfl_xor(m0, o));
    m1 = fmaxf(m1, __shfl_xor(m1, o));
    m2 = fmaxf(m2, __shfl_xor(m2, o));
    m3 = fmaxf(m3, __shfl_xor(m3, o));
  }
  __shared__ float4 red[8][8];
  if (lane < 8) red[w][lane] = (float4){m0, m1, m2, m3};
  __syncthreads();
  if (t < 8) {
    float4 a = red[0][t];
#pragma unroll
    for (int ww = 1; ww < 8; ww++) {
      float4 b = red[ww][t];
      a.x = fmaxf(a.x, b.x); a.y = fmaxf(a.y, b.y);
      a.z = fmaxf(a.z, b.z); a.w = fmaxf(a.w, b.w);
    }
    float v = (__expf(a.x) + __expf(a.y) + __expf(a.z) + __expf(a.w)) * (1.0f / (float)PP);
    v += __shfl_down(v, 4);
    v += __shfl_down(v, 2);
    v += __shfl_down(v, 1);
    if (t == 0) atomicAdd(&cxsum[n], v);
  }
}

// Kernel 6: CX_B = -log(cxsum), loss = mean
__global__ void k_final(const float* __restrict__ cxsum, float* __restrict__ out) {
  int t = threadIdx.x;
  float cxb = 0.f;
  if (t < 4) {
    cxb = -logf(cxsum[t]);
    out[1 + t] = cxb;
  }
  for (int o = 2; o > 0; o >>= 1) cxb += __shfl_down(cxb, o);
  if (t == 0) out[0] = cxb * 0.25f;
}

extern "C" void kernel_launch(void* const* d_in, const int* in_sizes, int n_in,
                              void* d_out, int out_size, void* d_ws, size_t ws_size,
                              hipStream_t stream) {
  const float* fT = (const float*)d_in[0];
  const float* fI = (const float*)d_in[1];
  float* out = (float*)d_out;

  char* w = (char*)d_ws;
  float* partial = (float*)w;                                    // 4096 B
  unsigned* divu = (unsigned*)(w + 4096);                        // 36864 B
  float* scale   = (float*)(w + 4096 + 36864);                   // 36864 B
  float* lnS     = (float*)(w + 4096 + 2 * 36864);               // 36864 B
  float* cxsum   = (float*)(w + 4096 + 3 * 36864);               // pad to 1024
  size_t off = 4096 + 3 * 36864 + 1024;                          // 115712
  unsigned short* A = (unsigned short*)(w + off);                // 4718592 B
  unsigned short* B = (unsigned short*)(w + off + 4718592);      // 4718592 B
  __half* rawt = (__half*)(w + off + 2 * 4718592);               // 42467328 B

  k_mean<<<dim3(CC, NN), 256, 0, stream>>>(fT, partial, divu, cxsum);
  k_norm<<<dim3(PP / 16, NN), 256, 0, stream>>>(fT, fI, partial, A, B);
  k_gemm<<<dim3(PP / 128, PP / 128, NN), 256, 0, stream>>>(A, B, rawt, divu);
  k_colsum<<<dim3(PP * NN / 4), 256, 0, stream>>>(rawt, divu, scale, lnS);
  k_rowmax<<<dim3(PP / 32, NN), 512, 0, stream>>>(rawt, scale, lnS, cxsum);
  k_final<<<1, 64, 0, stream>>>(cxsum, out);
}